// Round 1
// baseline (1692.819 us; speedup 1.0000x reference)
//
#include <hip/hip_runtime.h>

// VQ-VAE vector quantizer step on MI355X (gfx950).
// Round 1: correct f32 implementation. Distance GEMM on the vector ALU
// (no fp32 MFMA on CDNA4); 64x256 block tile, 8x8 micro-tile.

#define NT 131072   // tokens
#define NE 1024     // codebook entries
#define ED 256      // embedding dim

// Output layout (flat f32, reference return order)
static const size_t OFF_QL   = 0;            // quant_loss (1)
static const size_t OFF_CL   = 1;            // commit_loss (1)
static const size_t OFF_ZQ   = 2;            // z_q_st (131072*256)
static const size_t OFF_PPL  = 33554434ULL;  // perplexity (1)
static const size_t OFF_OH   = 33554435ULL;  // min_encodings (131072*1024)
static const size_t OFF_IDX  = 167772163ULL; // idx (131072)
static const size_t OFF_NEMB = 167903235ULL; // new_emb_weight (1024*256)
static const size_t OFF_NN   = 168165379ULL; // new_n_mat (1024)
static const size_t OFF_NM   = 168166403ULL; // new_m_mat (1024*256)

// ---------------------------------------------------------------- row norms
__global__ __launch_bounds__(256) void rownorm_k(const float* __restrict__ x,
                                                 float* __restrict__ o, int nrows) {
  int wid  = blockIdx.x * 4 + (threadIdx.x >> 6);  // one wave per row
  int lane = threadIdx.x & 63;
  if (wid >= nrows) return;
  float4 v = ((const float4*)(x + (size_t)wid * ED))[lane];
  float s = v.x * v.x + v.y * v.y + v.z * v.z + v.w * v.w;
  #pragma unroll
  for (int off = 32; off; off >>= 1) s += __shfl_down(s, off, 64);
  if (lane == 0) o[wid] = s;
}

// ------------------------------------------------- distance GEMM + argmin
// Block: 256 threads = (tr 0..7) x (tc 0..31). Tile: 64 tokens x 256 codes
// per code-tile iteration (4 iterations cover 1024 codes). K staged in
// 16-wide slices; z and e tiles stored K-major (transposed) so the 8x8
// micro-kernel does 4x ds_read_b128 per k-step (1 B LDS per FMA).
__global__ __launch_bounds__(256) void argmin_k(
    const float* __restrict__ z, const float* __restrict__ emb,
    const float* __restrict__ znorm, const float* __restrict__ enorm,
    int* __restrict__ idxw) {
  __shared__ float zs[16][68];    // [k][row], pad 64->68 keeps 16B align, 2-way banks (free)
  __shared__ float es[16][260];   // [k][col], pad 256->260
  __shared__ float rv[64][32];
  __shared__ int   ri[64][32];

  const int tid  = threadIdx.x;
  const int tr   = tid >> 5, tc = tid & 31;
  const int row0 = blockIdx.x * 64;
  const int zr   = tid >> 2, zk0 = (tid & 3) * 4;  // z staging map

  float zn[8];
  #pragma unroll
  for (int i = 0; i < 8; i++) zn[i] = znorm[row0 + tr * 8 + i];

  float minv[8]; int mini[8];
  #pragma unroll
  for (int i = 0; i < 8; i++) { minv[i] = 3.4028235e38f; mini[i] = 0; }

  for (int ct = 0; ct < 4; ++ct) {
    const int c0 = ct * 256;
    float en[8];
    #pragma unroll
    for (int j = 0; j < 8; j++) en[j] = enorm[c0 + tc * 8 + j];

    float acc[8][8];
    #pragma unroll
    for (int i = 0; i < 8; i++)
      #pragma unroll
      for (int j = 0; j < 8; j++) acc[i][j] = 0.f;

    for (int kt = 0; kt < 16; ++kt) {
      const int k0 = kt * 16;
      // global->reg staging loads (coalesced in 64B chunks)
      float4 zv = *(const float4*)(z + (size_t)(row0 + zr) * ED + k0 + zk0);
      const float* er = emb + (size_t)(c0 + tid) * ED + k0;
      float4 e0 = ((const float4*)er)[0];
      float4 e1 = ((const float4*)er)[1];
      float4 e2 = ((const float4*)er)[2];
      float4 e3 = ((const float4*)er)[3];
      __syncthreads();   // previous k-tile consumed
      zs[zk0 + 0][zr] = zv.x; zs[zk0 + 1][zr] = zv.y;
      zs[zk0 + 2][zr] = zv.z; zs[zk0 + 3][zr] = zv.w;
      es[0][tid] = e0.x;  es[1][tid] = e0.y;  es[2][tid] = e0.z;  es[3][tid] = e0.w;
      es[4][tid] = e1.x;  es[5][tid] = e1.y;  es[6][tid] = e1.z;  es[7][tid] = e1.w;
      es[8][tid] = e2.x;  es[9][tid] = e2.y;  es[10][tid] = e2.z; es[11][tid] = e2.w;
      es[12][tid] = e3.x; es[13][tid] = e3.y; es[14][tid] = e3.z; es[15][tid] = e3.w;
      __syncthreads();
      #pragma unroll
      for (int k = 0; k < 16; k++) {
        float a[8], b[8];
        *(float4*)&a[0] = *(const float4*)&zs[k][tr * 8];
        *(float4*)&a[4] = *(const float4*)&zs[k][tr * 8 + 4];
        *(float4*)&b[0] = *(const float4*)&es[k][tc * 8];
        *(float4*)&b[4] = *(const float4*)&es[k][tc * 8 + 4];
        #pragma unroll
        for (int i = 0; i < 8; i++)
          #pragma unroll
          for (int j = 0; j < 8; j++) acc[i][j] += a[i] * b[j];
      }
    }
    // d = (||z||^2 + ||e||^2) - 2*dot  (replicates reference op order)
    #pragma unroll
    for (int i = 0; i < 8; i++) {
      #pragma unroll
      for (int j = 0; j < 8; j++) {
        float s = zn[i] + en[j];
        float d = s - 2.0f * acc[i][j];
        int   c = c0 + tc * 8 + j;
        if (d < minv[i]) { minv[i] = d; mini[i] = c; }  // strict <: first-index tie-break
      }
    }
  }

  __syncthreads();
  #pragma unroll
  for (int i = 0; i < 8; i++) { rv[tr * 8 + i][tc] = minv[i]; ri[tr * 8 + i][tc] = mini[i]; }
  __syncthreads();
  if (tid < 64) {
    float bv = rv[tid][0]; int bi = ri[tid][0];
    for (int t = 1; t < 32; t++) {
      float v = rv[tid][t]; int ii = ri[tid][t];
      if (v < bv || (v == bv && ii < bi)) { bv = v; bi = ii; }
    }
    idxw[row0 + tid] = bi;
  }
}

// -------------------------------------------- per-token outputs + reductions
#define TPB 32
__global__ __launch_bounds__(256) void fin_tok_k(
    const float* __restrict__ z, const float* __restrict__ emb,
    const int* __restrict__ idxw, float* __restrict__ out,
    int* __restrict__ counts, float* __restrict__ msum,
    double* __restrict__ lossacc) {
  const int t = threadIdx.x;
  __shared__ double lred[4];
  double lsum = 0.0;
  const int tok0 = blockIdx.x * TPB;
  for (int tok = tok0; tok < tok0 + TPB; ++tok) {
    const int   id = idxw[tok];
    const float zv = z[(size_t)tok * ED + t];
    const float ev = emb[(size_t)id * ED + t];
    out[OFF_ZQ + (size_t)tok * ED + t] = zv + (ev - zv);  // straight-through, exact ref formula
    const float df = ev - zv;
    lsum += (double)(df * df);
    unsafeAtomicAdd(&msum[(size_t)id * ED + t], zv);      // segment_sum
    if (t == 0) {
      atomicAdd(&counts[id], 1);
      out[OFF_IDX + tok] = (float)id;
    }
    const size_t ohb = OFF_OH + (size_t)tok * NE;
    #pragma unroll
    for (int c = 0; c < 4; c++) {
      int col = t + 256 * c;
      out[ohb + col] = (col == id) ? 1.0f : 0.0f;
    }
  }
  #pragma unroll
  for (int off = 32; off; off >>= 1) lsum += __shfl_down(lsum, off, 64);
  if ((t & 63) == 0) lred[t >> 6] = lsum;
  __syncthreads();
  if (t == 0) unsafeAtomicAdd(lossacc, lred[0] + lred[1] + lred[2] + lred[3]);
}

// ------------------------------------------------------------- EMA updates
__global__ __launch_bounds__(256) void fin_code_k(
    const float* __restrict__ nmat, const float* __restrict__ mmat,
    const int* __restrict__ counts, const float* __restrict__ msum,
    float* __restrict__ out) {
  const int j = blockIdx.x, t = threadIdx.x;
  __shared__ float s_newn;
  if (t == 0) {
    float newn = nmat[j] * 0.99f + (float)counts[j] * 0.01f;
    out[OFF_NN + j] = newn;
    s_newn = newn;
  }
  __syncthreads();
  const size_t o = (size_t)j * ED + t;
  float newm = 0.99f * mmat[o] + 0.01f * msum[o];
  out[OFF_NM + o]   = newm;
  out[OFF_NEMB + o] = newm / s_newn;
}

// ------------------------------------------------------- scalar finalizers
__global__ __launch_bounds__(256) void scalars_k(
    const double* __restrict__ lossacc, const int* __restrict__ counts,
    float* __restrict__ out) {
  const int t = threadIdx.x;
  __shared__ double sh[4];
  if (t == 0) {
    double mean = *lossacc / (double)((size_t)NT * ED);
    out[OFF_QL] = (float)mean;          // quant_loss
    out[OFF_CL] = (float)(0.25 * mean); // commit_loss = BETA * same mean
  }
  double h = 0.0;
  for (int c = t; c < NE; c += 256) {
    double e = (double)counts[c] / (double)NT;
    h += e * log(e + 1e-10);
  }
  #pragma unroll
  for (int off = 32; off; off >>= 1) h += __shfl_down(h, off, 64);
  if ((t & 63) == 0) sh[t >> 6] = h;
  __syncthreads();
  if (t == 0) out[OFF_PPL] = (float)exp(-(sh[0] + sh[1] + sh[2] + sh[3]));
}

// ------------------------------------------------------------------ launch
extern "C" void kernel_launch(void* const* d_in, const int* in_sizes, int n_in,
                              void* d_out, int out_size, void* d_ws, size_t ws_size,
                              hipStream_t stream) {
  const float* z    = (const float*)d_in[0];
  const float* emb  = (const float*)d_in[1];
  const float* nmat = (const float*)d_in[2];
  const float* mmat = (const float*)d_in[3];
  float* out = (float*)d_out;
  char*  ws  = (char*)d_ws;

  // ws layout: [loss f64 8B][counts 4KB][msum 1MB][idx 512KB][znorm 512KB][enorm 4KB]
  double* lossacc = (double*)ws;
  int*    counts  = (int*)(ws + 8);
  float*  msum    = (float*)(ws + 8 + 4096);
  int*    idxw    = (int*)(ws + 8 + 4096 + 1048576);
  float*  znorm   = (float*)(ws + 8 + 4096 + 1048576 + 524288);
  float*  enorm   = znorm + NT;

  hipMemsetAsync(ws, 0, 8 + 4096 + 1048576, stream);  // zero loss+counts+msum

  hipLaunchKernelGGL(rownorm_k, dim3(NT / 4), dim3(256), 0, stream, z, znorm, NT);
  hipLaunchKernelGGL(rownorm_k, dim3(NE / 4), dim3(256), 0, stream, emb, enorm, NE);
  hipLaunchKernelGGL(argmin_k, dim3(NT / 64), dim3(256), 0, stream,
                     z, emb, znorm, enorm, idxw);
  hipLaunchKernelGGL(fin_tok_k, dim3(NT / TPB), dim3(256), 0, stream,
                     z, emb, idxw, out, counts, msum, lossacc);
  hipLaunchKernelGGL(fin_code_k, dim3(NE), dim3(256), 0, stream,
                     nmat, mmat, counts, msum, out);
  hipLaunchKernelGGL(scalars_k, dim3(1), dim3(256), 0, stream,
                     lossacc, counts, out);
}

// Round 2
// 1660.431 us; speedup vs baseline: 1.0195x; 1.0195x over previous
//
#include <hip/hip_runtime.h>

// VQ-VAE vector quantizer step on MI355X (gfx950).
// Round 2: epilogue restructure — no contended atomics.
//   - zq_oh_k: streaming z_q + one-hot + idx + loss partials (f64, 256 slots)
//   - hist/scan/scatter: counting-sort tokens by code
//   - segsum_k: per-code bucket walk (no atomics) fused with EMA update
// argmin_k unchanged from round 1 (855us; MFMA split-bf16 path is next).

#define NT 131072   // tokens
#define NE 1024     // codebook entries
#define ED 256      // embedding dim

// Output layout (flat f32, reference return order)
static const size_t OFF_QL   = 0;            // quant_loss (1)
static const size_t OFF_CL   = 1;            // commit_loss (1)
static const size_t OFF_ZQ   = 2;            // z_q_st (131072*256)
static const size_t OFF_PPL  = 33554434ULL;  // perplexity (1)
static const size_t OFF_OH   = 33554435ULL;  // min_encodings (131072*1024)
static const size_t OFF_IDX  = 167772163ULL; // idx (131072)
static const size_t OFF_NEMB = 167903235ULL; // new_emb_weight (1024*256)
static const size_t OFF_NN   = 168165379ULL; // new_n_mat (1024)
static const size_t OFF_NM   = 168166403ULL; // new_m_mat (1024*256)

// ---------------------------------------------------------------- row norms
__global__ __launch_bounds__(256) void rownorm_k(const float* __restrict__ x,
                                                 float* __restrict__ o, int nrows) {
  int wid  = blockIdx.x * 4 + (threadIdx.x >> 6);  // one wave per row
  int lane = threadIdx.x & 63;
  if (wid >= nrows) return;
  float4 v = ((const float4*)(x + (size_t)wid * ED))[lane];
  float s = v.x * v.x + v.y * v.y + v.z * v.z + v.w * v.w;
  #pragma unroll
  for (int off = 32; off; off >>= 1) s += __shfl_down(s, off, 64);
  if (lane == 0) o[wid] = s;
}

// ------------------------------------------------- distance GEMM + argmin
// (unchanged from round 1)
__global__ __launch_bounds__(256) void argmin_k(
    const float* __restrict__ z, const float* __restrict__ emb,
    const float* __restrict__ znorm, const float* __restrict__ enorm,
    int* __restrict__ idxw) {
  __shared__ float zs[16][68];
  __shared__ float es[16][260];
  __shared__ float rv[64][32];
  __shared__ int   ri[64][32];

  const int tid  = threadIdx.x;
  const int tr   = tid >> 5, tc = tid & 31;
  const int row0 = blockIdx.x * 64;
  const int zr   = tid >> 2, zk0 = (tid & 3) * 4;

  float zn[8];
  #pragma unroll
  for (int i = 0; i < 8; i++) zn[i] = znorm[row0 + tr * 8 + i];

  float minv[8]; int mini[8];
  #pragma unroll
  for (int i = 0; i < 8; i++) { minv[i] = 3.4028235e38f; mini[i] = 0; }

  for (int ct = 0; ct < 4; ++ct) {
    const int c0 = ct * 256;
    float en[8];
    #pragma unroll
    for (int j = 0; j < 8; j++) en[j] = enorm[c0 + tc * 8 + j];

    float acc[8][8];
    #pragma unroll
    for (int i = 0; i < 8; i++)
      #pragma unroll
      for (int j = 0; j < 8; j++) acc[i][j] = 0.f;

    for (int kt = 0; kt < 16; ++kt) {
      const int k0 = kt * 16;
      float4 zv = *(const float4*)(z + (size_t)(row0 + zr) * ED + k0 + zk0);
      const float* er = emb + (size_t)(c0 + tid) * ED + k0;
      float4 e0 = ((const float4*)er)[0];
      float4 e1 = ((const float4*)er)[1];
      float4 e2 = ((const float4*)er)[2];
      float4 e3 = ((const float4*)er)[3];
      __syncthreads();
      zs[zk0 + 0][zr] = zv.x; zs[zk0 + 1][zr] = zv.y;
      zs[zk0 + 2][zr] = zv.z; zs[zk0 + 3][zr] = zv.w;
      es[0][tid] = e0.x;  es[1][tid] = e0.y;  es[2][tid] = e0.z;  es[3][tid] = e0.w;
      es[4][tid] = e1.x;  es[5][tid] = e1.y;  es[6][tid] = e1.z;  es[7][tid] = e1.w;
      es[8][tid] = e2.x;  es[9][tid] = e2.y;  es[10][tid] = e2.z; es[11][tid] = e2.w;
      es[12][tid] = e3.x; es[13][tid] = e3.y; es[14][tid] = e3.z; es[15][tid] = e3.w;
      __syncthreads();
      #pragma unroll
      for (int k = 0; k < 16; k++) {
        float a[8], b[8];
        *(float4*)&a[0] = *(const float4*)&zs[k][tr * 8];
        *(float4*)&a[4] = *(const float4*)&zs[k][tr * 8 + 4];
        *(float4*)&b[0] = *(const float4*)&es[k][tc * 8];
        *(float4*)&b[4] = *(const float4*)&es[k][tc * 8 + 4];
        #pragma unroll
        for (int i = 0; i < 8; i++)
          #pragma unroll
          for (int j = 0; j < 8; j++) acc[i][j] += a[i] * b[j];
      }
    }
    #pragma unroll
    for (int i = 0; i < 8; i++) {
      #pragma unroll
      for (int j = 0; j < 8; j++) {
        float s = zn[i] + en[j];
        float d = s - 2.0f * acc[i][j];
        int   c = c0 + tc * 8 + j;
        if (d < minv[i]) { minv[i] = d; mini[i] = c; }
      }
    }
  }

  __syncthreads();
  #pragma unroll
  for (int i = 0; i < 8; i++) { rv[tr * 8 + i][tc] = minv[i]; ri[tr * 8 + i][tc] = mini[i]; }
  __syncthreads();
  if (tid < 64) {
    float bv = rv[tid][0]; int bi = ri[tid][0];
    for (int t = 1; t < 32; t++) {
      float v = rv[tid][t]; int ii = ri[tid][t];
      if (v < bv || (v == bv && ii < bi)) { bv = v; bi = ii; }
    }
    idxw[row0 + tid] = bi;
  }
}

// ------------------------- streaming per-token outputs: z_q, one-hot, idx, loss
__global__ __launch_bounds__(256) void zq_oh_k(
    const float* __restrict__ z, const float* __restrict__ emb,
    const int* __restrict__ idxw, float* __restrict__ out,
    double* __restrict__ lossacc) {
  const int t = threadIdx.x;
  const int tl = t >> 6, lane = t & 63;
  const int tok = blockIdx.x * 4 + tl;
  const int id = idxw[tok];

  float4 z4 = ((const float4*)(z   + (size_t)tok * ED))[lane];
  float4 e4 = ((const float4*)(emb + (size_t)id  * ED))[lane];
  float4 q;
  q.x = z4.x + (e4.x - z4.x);   // straight-through, exact ref formula
  q.y = z4.y + (e4.y - z4.y);
  q.z = z4.z + (e4.z - z4.z);
  q.w = z4.w + (e4.w - z4.w);
  ((float4*)(out + OFF_ZQ + (size_t)tok * ED))[lane] = q;

  float dx = e4.x - z4.x, dy = e4.y - z4.y, dz = e4.z - z4.z, dw = e4.w - z4.w;
  double lsum = (double)(dx * dx) + (double)(dy * dy)
              + (double)(dz * dz) + (double)(dw * dw);

  // one-hot row (streaming float4 writes, value computed in-register)
  float* ohb = out + OFF_OH + (size_t)tok * NE;
  #pragma unroll
  for (int it = 0; it < 4; ++it) {
    int f4i = it * 64 + lane;
    int c0 = f4i * 4;
    float4 v;
    v.x = (c0 + 0 == id) ? 1.0f : 0.0f;
    v.y = (c0 + 1 == id) ? 1.0f : 0.0f;
    v.z = (c0 + 2 == id) ? 1.0f : 0.0f;
    v.w = (c0 + 3 == id) ? 1.0f : 0.0f;
    ((float4*)ohb)[f4i] = v;
  }
  if (lane == 0) out[OFF_IDX + tok] = (float)id;

  #pragma unroll
  for (int off = 32; off; off >>= 1) lsum += __shfl_down(lsum, off, 64);
  __shared__ double lred[4];
  if (lane == 0) lred[tl] = lsum;
  __syncthreads();
  if (t == 0)
    unsafeAtomicAdd(&lossacc[blockIdx.x & 255],
                    lred[0] + lred[1] + lred[2] + lred[3]);
}

// ------------------------------------------------ histogram (LDS-privatized)
__global__ __launch_bounds__(256) void hist_k(const int* __restrict__ idxw,
                                              int* __restrict__ counts) {
  __shared__ int lc[NE];
  for (int i = threadIdx.x; i < NE; i += 256) lc[i] = 0;
  __syncthreads();
  const int stride = gridDim.x * 256;
  for (int i = blockIdx.x * 256 + threadIdx.x; i < NT; i += stride)
    atomicAdd(&lc[idxw[i]], 1);
  __syncthreads();
  for (int i = threadIdx.x; i < NE; i += 256) {
    int v = lc[i];
    if (v) atomicAdd(&counts[i], v);
  }
}

// -------------------------------------------------------- exclusive prefix sum
__global__ void scan_k(const int* __restrict__ counts, int* __restrict__ offsets) {
  if (threadIdx.x == 0) {
    int s = 0;
    for (int i = 0; i < NE; i++) { offsets[i] = s; s += counts[i]; }
  }
}

// -------------------------------------------------- scatter tokens into buckets
__global__ __launch_bounds__(256) void scatter_k(
    const int* __restrict__ idxw, const int* __restrict__ offsets,
    int* __restrict__ cursor, int* __restrict__ bucket) {
  int i = blockIdx.x * 256 + threadIdx.x;
  int id = idxw[i];
  int pos = atomicAdd(&cursor[id], 1);
  bucket[offsets[id] + pos] = i;
}

// ------------------- per-code segment sum (no atomics) fused with EMA update
__global__ __launch_bounds__(256) void segsum_k(
    const float* __restrict__ z, const float* __restrict__ nmat,
    const float* __restrict__ mmat, const int* __restrict__ counts,
    const int* __restrict__ offsets, const int* __restrict__ bucket,
    float* __restrict__ out) {
  const int j = blockIdx.x, t = threadIdx.x;
  const int cnt = counts[j], off = offsets[j];
  float s = 0.f;
  int i = 0;
  for (; i + 4 <= cnt; i += 4) {   // unroll x4: overlap the 4 row gathers
    int t0 = bucket[off + i + 0], t1 = bucket[off + i + 1];
    int t2 = bucket[off + i + 2], t3 = bucket[off + i + 3];
    float a = z[(size_t)t0 * ED + t];
    float b = z[(size_t)t1 * ED + t];
    float c = z[(size_t)t2 * ED + t];
    float d = z[(size_t)t3 * ED + t];
    s += a; s += b; s += c; s += d;
  }
  for (; i < cnt; ++i) s += z[(size_t)bucket[off + i] * ED + t];

  float newn = nmat[j] * 0.99f + (float)cnt * 0.01f;
  if (t == 0) out[OFF_NN + j] = newn;
  const size_t o = (size_t)j * ED + t;
  float newm = 0.99f * mmat[o] + 0.01f * s;
  out[OFF_NM + o]   = newm;
  out[OFF_NEMB + o] = newm / newn;
}

// ------------------------------------------------------- scalar finalizers
__global__ __launch_bounds__(256) void scalars_k(
    const double* __restrict__ lossacc, const int* __restrict__ counts,
    float* __restrict__ out) {
  const int t = threadIdx.x;
  double lsum = lossacc[t];
  double h = 0.0;
  for (int c = t; c < NE; c += 256) {
    double e = (double)counts[c] / (double)NT;
    h += e * log(e + 1e-10);
  }
  #pragma unroll
  for (int off = 32; off; off >>= 1) {
    lsum += __shfl_down(lsum, off, 64);
    h    += __shfl_down(h,    off, 64);
  }
  __shared__ double sl[4], sh[4];
  if ((t & 63) == 0) { sl[t >> 6] = lsum; sh[t >> 6] = h; }
  __syncthreads();
  if (t == 0) {
    double mean = (sl[0] + sl[1] + sl[2] + sl[3]) / (double)((size_t)NT * ED);
    out[OFF_QL]  = (float)mean;
    out[OFF_CL]  = (float)(0.25 * mean);
    out[OFF_PPL] = (float)exp(-(sh[0] + sh[1] + sh[2] + sh[3]));
  }
}

// ------------------------------------------------------------------ launch
extern "C" void kernel_launch(void* const* d_in, const int* in_sizes, int n_in,
                              void* d_out, int out_size, void* d_ws, size_t ws_size,
                              hipStream_t stream) {
  const float* z    = (const float*)d_in[0];
  const float* emb  = (const float*)d_in[1];
  const float* nmat = (const float*)d_in[2];
  const float* mmat = (const float*)d_in[3];
  float* out = (float*)d_out;
  char*  ws  = (char*)d_ws;

  // ws layout (byte offsets):
  //   0       lossacc  double[256]  (2 KB, pad to 4 KB)
  //   4096    counts   int[1024]
  //   8192    cursor   int[1024]
  //   12288   offsets  int[1024]
  //   16384   bucket   int[131072]  (512 KB)
  //   540672  idxw     int[131072]  (512 KB)
  //   1064960 znorm    float[131072] (512 KB)
  //   1589248 enorm    float[1024]  (4 KB)
  double* lossacc = (double*)ws;
  int*    counts  = (int*)(ws + 4096);
  int*    cursor  = (int*)(ws + 8192);
  int*    offsets = (int*)(ws + 12288);
  int*    bucket  = (int*)(ws + 16384);
  int*    idxw    = (int*)(ws + 540672);
  float*  znorm   = (float*)(ws + 1064960);
  float*  enorm   = (float*)(ws + 1589248);

  hipMemsetAsync(ws, 0, 12288, stream);  // lossacc + counts + cursor

  hipLaunchKernelGGL(rownorm_k, dim3(NT / 4), dim3(256), 0, stream, z, znorm, NT);
  hipLaunchKernelGGL(rownorm_k, dim3(NE / 4), dim3(256), 0, stream, emb, enorm, NE);
  hipLaunchKernelGGL(argmin_k, dim3(NT / 64), dim3(256), 0, stream,
                     z, emb, znorm, enorm, idxw);
  hipLaunchKernelGGL(zq_oh_k, dim3(NT / 4), dim3(256), 0, stream,
                     z, emb, idxw, out, lossacc);
  hipLaunchKernelGGL(hist_k, dim3(64), dim3(256), 0, stream, idxw, counts);
  hipLaunchKernelGGL(scan_k, dim3(1), dim3(64), 0, stream, counts, offsets);
  hipLaunchKernelGGL(scatter_k, dim3(NT / 256), dim3(256), 0, stream,
                     idxw, offsets, cursor, bucket);
  hipLaunchKernelGGL(segsum_k, dim3(NE), dim3(256), 0, stream,
                     z, nmat, mmat, counts, offsets, bucket, out);
  hipLaunchKernelGGL(scalars_k, dim3(1), dim3(256), 0, stream,
                     lossacc, counts, out);
}